// Round 1
// 282.499 us; speedup vs baseline: 1.0453x; 1.0453x over previous
//
#include <hip/hip_runtime.h>

// Lyapunov spectrum, closed form.
//
// Key identity: the reference's per-step row-GS norms of M = A*Q depend only
// on the Gram matrix M*M^T = A*Q*Q^T*A^T = A*A^T (Q stays exactly orthonormal:
// induction from Q0 = I, GS re-orthonormalizes every step). Therefore the
// output is independent of the Q recursion entirely -> no serial dependence,
// no warm-up, no chunking. Per step, with a10 = dt*(28-z), a12 = -dt*x:
//   n0  = 0.9^2 + 0.1^2 = 0.82                        (constant -> lam0 = 50*ln0.82)
//   d1  = 0.9*a10 + 0.099
//   n1  = 0.9801 + a10^2 + (dt*x)^2
//   nr1 = n1 - d1^2/0.82                              (squared GS norm of row 1)
//   n2  = det(A)^2 / (0.82 * nr1)                     (Gram determinant identity)
//   det(A) = 0.891*a22 - 0.1*a22*a10 + 0.9*dt^2*x^2 - 0.1*dt^2*x*y
//          = 0.86724 - 0.09733333*a10 + 9e-5*x^2 - 1e-5*x*y   (> 0 always)
// Logs are deferred via running products (bounded: nr1 in ~[0.89,0.93],
// det in ~[0.83,0.85]; over 8 steps products stay in [0.2, 0.5] -> fp32 safe).

#define T_STEPS 2048
#define B_CH    8192
#define DT_F    0.01f
#define SLICES  256
#define SPT     (T_STEPS / SLICES)   // 8 timesteps per thread
#define QUADS   (B_CH / 4)           // 2048 float4 chain-quads

typedef float v2f __attribute__((ext_vector_type(2)));
typedef float v4f __attribute__((ext_vector_type(4)));

__device__ __forceinline__ float fast_log2(float x) { return __builtin_amdgcn_logf(x); }

__device__ __forceinline__ void step_pair(v2f x, v2f y, v2f z, v2f& P1, v2f& PD) {
  const float INV082 = 1.2195122f;            // 1/0.82
  v2f a10 = 0.28f - DT_F * z;                 // dt*(28-z)
  v2f xx  = x * x;
  v2f xy  = x * y;
  v2f n1  = 0.9801f + 1.0e-4f * xx;           // + (dt*x)^2
  n1      = n1 + a10 * a10;
  v2f d1  = 0.099f + 0.9f * a10;
  v2f t   = d1 * INV082;
  v2f nr1 = n1 - t * d1;                      // n1 - d1^2/0.82
  P1 *= nr1;
  v2f det = 0.86724f - 0.09733333f * a10;     // a22*(0.891 - 0.1*a10)
  det     = det + 9.0e-5f * xx;
  det     = det - 1.0e-5f * xy;
  PD *= det;
}

// Grid: (QUADS/256, SLICES) x 256. Pure streaming reduction: each thread owns
// 4 chains (one float4 lane-slot) for 8 timesteps; 16B/lane coalesced loads.
// Memory-bound by ~8x -> target is the HBM roofline (~201 MB once, ~33 us).
__global__ __launch_bounds__(256) void lyap_stream_kernel(const float* __restrict__ traj,
                                                          float* __restrict__ ws) {
  const int q = blockIdx.x * 256 + threadIdx.x;     // chain-quad id, 0..QUADS-1
  const int s = blockIdx.y;                          // time slice, 0..SLICES-1
  const v4f* __restrict__ p =
      (const v4f*)traj + (size_t)(s * SPT) * (3 * QUADS) + q;

  v2f P1a = 1.f, P1b = 1.f, PDa = 1.f, PDb = 1.f;
#pragma unroll
  for (int i = 0; i < SPT; ++i) {
    v4f X = p[(i * 3 + 0) * QUADS];
    v4f Y = p[(i * 3 + 1) * QUADS];
    v4f Z = p[(i * 3 + 2) * QUADS];
    v2f xa = {X.x, X.y}, xb = {X.z, X.w};
    v2f ya = {Y.x, Y.y}, yb = {Y.z, Y.w};
    v2f za = {Z.x, Z.y}, zb = {Z.z, Z.w};
    step_pair(xa, ya, za, P1a, PDa);
    step_pair(xb, yb, zb, P1b, PDb);
  }

  v4f h1, hD;
  h1.x = fast_log2(P1a.x); h1.y = fast_log2(P1a.y);
  h1.z = fast_log2(P1b.x); h1.w = fast_log2(P1b.y);
  hD.x = fast_log2(PDa.x); hD.y = fast_log2(PDa.y);
  hD.z = fast_log2(PDb.x); hD.w = fast_log2(PDb.y);

  v4f* __restrict__ w1 = (v4f*)ws;                   // [SLICES][QUADS] log2-partials of nr1
  v4f* __restrict__ wD = w1 + SLICES * QUADS;        // [SLICES][QUADS] log2-partials of det
  w1[s * QUADS + q] = h1;
  wD[s * QUADS + q] = hD;
}

__global__ __launch_bounds__(256) void lyap_reduce_kernel(const float* __restrict__ ws,
                                                          float* __restrict__ out) {
  const int c = blockIdx.x * 256 + threadIdx.x;      // chain, 0..B_CH-1
  const float* __restrict__ w1 = ws;
  const float* __restrict__ wD = ws + (size_t)SLICES * B_CH;
  float H1 = 0.f, HD = 0.f;
#pragma unroll 8
  for (int s = 0; s < SLICES; ++s) {
    H1 += w1[s * B_CH + c];
    HD += wD[s * B_CH + c];
  }
  // lam = 0.5*ln(n^2)-sums / (T*DT); log2 -> ln via 0.5*ln2.
  const float scale = 0.5f * 0.69314718f / (T_STEPS * DT_F);
  const float LAM0  = -9.9225470f;                   // 50*ln(0.82), exact closed form
  out[c]            = LAM0;
  out[B_CH + c]     = scale * H1;
  // sum log2 n2 = 2*HD - 2048*log2(0.82) - H1; scale*2048*log2(0.82) == LAM0
  out[2 * B_CH + c] = scale * (2.f * HD - H1) - LAM0;
}

extern "C" void kernel_launch(void* const* d_in, const int* in_sizes, int n_in,
                              void* d_out, int out_size, void* d_ws, size_t ws_size,
                              hipStream_t stream) {
  (void)in_sizes; (void)n_in; (void)out_size; (void)ws_size;
  const float* traj = (const float*)d_in[0];
  float* out = (float*)d_out;
  float* ws  = (float*)d_ws;   // 2 * SLICES * B_CH * 4 B = 16.8 MB

  lyap_stream_kernel<<<dim3(QUADS / 256, SLICES), dim3(256), 0, stream>>>(traj, ws);
  lyap_reduce_kernel<<<dim3(B_CH / 256), dim3(256), 0, stream>>>(ws, out);
}

// Round 2
// 270.051 us; speedup vs baseline: 1.0934x; 1.0461x over previous
//
#include <hip/hip_runtime.h>

// Lyapunov spectrum, closed form.
//
// Key identity: the reference's per-step row-GS norms of M = A*Q depend only
// on the Gram matrix M*M^T = A*Q*Q^T*A^T = A*A^T (Q stays exactly orthonormal:
// induction from Q0 = I, GS re-orthonormalizes every step). Therefore the
// output is independent of the Q recursion entirely -> no serial dependence,
// no warm-up, no chunking. Per step, with a10 = dt*(28-z):
//   n0  = 0.9^2 + 0.1^2 = 0.82                        (constant -> lam0 = 50*ln0.82)
//   d1  = 0.9*a10 + 0.099
//   n1  = 0.9801 + a10^2 + (dt*x)^2
//   nr1 = n1 - d1^2/0.82                              (squared GS norm of row 1)
//   n2  = det(A)^2 / (0.82 * nr1)                     (Gram determinant identity)
//   det(A) = 0.86724 - 0.09733333*a10 + 9e-5*x^2 - 1e-5*x*y   (> 0 always)
// Logs deferred via running products, harvested every 8 steps (products stay
// in [0.2, 0.5] per 8 steps -> fp32 safe).

#define T_STEPS 2048
#define B_CH    8192
#define DT_F    0.01f
#define SLICES  128
#define SPT     (T_STEPS / SLICES)   // 16 timesteps per thread
#define QUADS   (B_CH / 4)           // 2048 float4 chain-quads

typedef float v2f __attribute__((ext_vector_type(2)));
typedef float v4f __attribute__((ext_vector_type(4)));

__device__ __forceinline__ float fast_log2(float x) { return __builtin_amdgcn_logf(x); }

__device__ __forceinline__ void step_pair(v2f x, v2f y, v2f z, v2f& P1, v2f& PD) {
  const float INV082 = 1.2195122f;            // 1/0.82
  v2f a10 = 0.28f - DT_F * z;                 // dt*(28-z)
  v2f xx  = x * x;
  v2f xy  = x * y;
  v2f n1  = 0.9801f + 1.0e-4f * xx;           // + (dt*x)^2
  n1      = n1 + a10 * a10;
  v2f d1  = 0.099f + 0.9f * a10;
  v2f t   = d1 * INV082;
  v2f nr1 = n1 - t * d1;                      // n1 - d1^2/0.82
  P1 *= nr1;
  v2f det = 0.86724f - 0.09733333f * a10;     // a22*(0.891 - 0.1*a10)
  det     = det + 9.0e-5f * xx;
  det     = det - 1.0e-5f * xy;
  PD *= det;
}

// Grid: (QUADS/256, SLICES) x 256 = 262144 threads (16 waves/CU). Pure
// streaming reduction: each thread owns 4 chains (one float4 lane-slot) for
// 16 timesteps; 16B/lane coalesced loads. Memory-bound -> HBM roofline
// (~201 MB input + 8.4 MB partials ~ 33 us).
__global__ __launch_bounds__(256) void lyap_stream_kernel(const float* __restrict__ traj,
                                                          float* __restrict__ ws) {
  const int q = blockIdx.x * 256 + threadIdx.x;     // chain-quad id, 0..QUADS-1
  const int s = blockIdx.y;                          // time slice, 0..SLICES-1
  const v4f* __restrict__ p =
      (const v4f*)traj + (size_t)(s * SPT) * (3 * QUADS) + q;

  v4f h1 = {0.f, 0.f, 0.f, 0.f}, hD = {0.f, 0.f, 0.f, 0.f};

#pragma unroll 1
  for (int g = 0; g < SPT / 8; ++g) {               // rolled: bounds VGPR use
    v2f P1a = 1.f, P1b = 1.f, PDa = 1.f, PDb = 1.f;
    const v4f* pg = p + (size_t)(g * 8) * (3 * QUADS);
#pragma unroll
    for (int i = 0; i < 8; ++i) {
      v4f X = pg[(i * 3 + 0) * QUADS];
      v4f Y = pg[(i * 3 + 1) * QUADS];
      v4f Z = pg[(i * 3 + 2) * QUADS];
      v2f xa = {X.x, X.y}, xb = {X.z, X.w};
      v2f ya = {Y.x, Y.y}, yb = {Y.z, Y.w};
      v2f za = {Z.x, Z.y}, zb = {Z.z, Z.w};
      step_pair(xa, ya, za, P1a, PDa);
      step_pair(xb, yb, zb, P1b, PDb);
    }
    h1.x += fast_log2(P1a.x); h1.y += fast_log2(P1a.y);
    h1.z += fast_log2(P1b.x); h1.w += fast_log2(P1b.y);
    hD.x += fast_log2(PDa.x); hD.y += fast_log2(PDa.y);
    hD.z += fast_log2(PDb.x); hD.w += fast_log2(PDb.y);
  }

  v4f* __restrict__ w1 = (v4f*)ws;                   // [SLICES][QUADS] log2-partials of nr1
  v4f* __restrict__ wD = w1 + SLICES * QUADS;        // [SLICES][QUADS] log2-partials of det
  w1[s * QUADS + q] = h1;
  wD[s * QUADS + q] = hD;
}

// 128 blocks x 64 threads: one wave per block, 128 CUs active. Lanes read
// consecutive chains -> coalesced 256B rows; 8.4 MB total, L3-resident.
__global__ __launch_bounds__(64) void lyap_reduce_kernel(const float* __restrict__ ws,
                                                         float* __restrict__ out) {
  const int c = blockIdx.x * 64 + threadIdx.x;       // chain, 0..B_CH-1
  const float* __restrict__ w1 = ws;
  const float* __restrict__ wD = ws + (size_t)SLICES * B_CH;
  float H1 = 0.f, HD = 0.f;
#pragma unroll 8
  for (int s = 0; s < SLICES; ++s) {
    H1 += w1[s * B_CH + c];
    HD += wD[s * B_CH + c];
  }
  // lam = 0.5*ln(n^2)-sums / (T*DT); log2 -> ln via 0.5*ln2.
  const float scale = 0.5f * 0.69314718f / (T_STEPS * DT_F);
  const float LAM0  = -9.9225470f;                   // 50*ln(0.82), exact closed form
  out[c]            = LAM0;
  out[B_CH + c]     = scale * H1;
  // sum log2 n2 = 2*HD - 2048*log2(0.82) - H1; scale*2048*log2(0.82) == LAM0
  out[2 * B_CH + c] = scale * (2.f * HD - H1) - LAM0;
}

extern "C" void kernel_launch(void* const* d_in, const int* in_sizes, int n_in,
                              void* d_out, int out_size, void* d_ws, size_t ws_size,
                              hipStream_t stream) {
  (void)in_sizes; (void)n_in; (void)out_size; (void)ws_size;
  const float* traj = (const float*)d_in[0];
  float* out = (float*)d_out;
  float* ws  = (float*)d_ws;   // 2 * SLICES * B_CH * 4 B = 8.4 MB

  lyap_stream_kernel<<<dim3(QUADS / 256, SLICES), dim3(256), 0, stream>>>(traj, ws);
  lyap_reduce_kernel<<<dim3(B_CH / 64), dim3(64), 0, stream>>>(ws, out);
}